// Round 9
// baseline (7549.644 us; speedup 1.0000x reference)
//
#include <hip/hip_runtime.h>
#include <hip/hip_bf16.h>

#define DI __device__ __forceinline__

typedef short bf16x8 __attribute__((ext_vector_type(8)));
typedef float f32x4 __attribute__((ext_vector_type(4)));

constexpr int B_ = 2048, T_ = 120, V_ = 64, E_ = 128, H_ = 512, LAT_ = 256;
constexpr int H3 = 1536;  // 3*H

DI short f2b(float f) {
  union { __hip_bfloat16 h; short s; } u;
  u.h = __float2bfloat16(f);
  return u.s;
}
DI float b2f(short s) {
  union { unsigned u; float f; } x;
  x.u = (unsigned)(unsigned short)s << 16;
  return x.f;
}
DI float sigm(float x) { return 1.f / (1.f + __expf(-x)); }
DI float tanh_f(float x) {
  x = fminf(15.f, fmaxf(-15.f, x));
  float e = __expf(2.f * x);
  return (e - 1.f) / (e + 1.f);
}
DI float gru_one(float xr, float xz, float xn, float hr, float hz, float hn, float hp) {
  float r = sigm(xr + hr);
  float u = sigm(xz + hz);
  float nn = tanh_f(xn + r * hn);
  return (1.f - u) * nn + u * hp;
}
// pre-summed form: sr = xr+hr, sz = xz+hz; xn, hn separate
DI float gru_pre(float sr, float sz, float xn, float hn, float hp) {
  float r = sigm(sr);
  float u = sigm(sz);
  float nn = tanh_f(xn + r * hn);
  return (1.f - u) * nn + u * hp;
}

// ======== register staging: global -> regs -> swizzled ds_write (256 threads) ========
template <int ROWS, int BK, int NV>
DI void rs_load(const short* __restrict__ G, int row0, int K, int kk, bf16x8 (&v)[NV]) {
  constexpr int SLOTS = BK / 8;
  constexpr int RPP = 2048 / BK;
  static_assert(NV == ROWS / RPP, "NV mismatch");
  const int tid = threadIdx.x;
  const int rl = tid / SLOTS, sl = tid % SLOTS;
#pragma unroll
  for (int p = 0; p < NV; ++p)
    v[p] = *(const bf16x8*)(G + (size_t)(row0 + p * RPP + rl) * K + kk + sl * 8);
}
template <int ROWS, int BK, int NV>
DI void rs_write(char* __restrict__ lds, bf16x8 (&v)[NV]) {
  constexpr int SLOTS = BK / 8;
  constexpr int RPP = 2048 / BK;
  const int tid = threadIdx.x;
  const int rl = tid / SLOTS, sl = tid % SLOTS;
#pragma unroll
  for (int p = 0; p < NV; ++p) {
    int row = p * RPP + rl;
    *(bf16x8*)(lds + row * (SLOTS * 16) + ((sl ^ (row & (SLOTS - 1))) * 16)) = v[p];
  }
}
template <int BK>
DI bf16x8 fragL(const char* __restrict__ lds, int row, int kk) {
  return *(const bf16x8*)(lds + row * (BK * 2) + ((kk << 1) ^ ((row & (BK / 8 - 1)) << 4)));
}

// ======== core 128x128 GEMM: acc = A[128x512] @ W[128x512]^T, BK=32 dbuf (32KB) ========
// 4 waves 2x2, wave tile 64x64, acc[4][4]; one barrier per chunk, 16 MFMA/chunk/wave.
DI void gemm128(const short* __restrict__ A, const short* __restrict__ Bw,
                int arow, int bcol, char* lds, f32x4 (&acc)[4][4]) {
  char* As[2] = {lds, lds + 8192};
  char* Bs[2] = {lds + 16384, lds + 24576};
  const int tid = threadIdx.x, lane = tid & 63, wid = tid >> 6;
  const int wm = wid >> 1, wn = wid & 1;
  const int r = lane & 15, ko = (lane >> 4) * 8;
  bf16x8 va[2], vb[2];
  rs_load<128, 32, 2>(A, arow, H_, 0, va);
  rs_load<128, 32, 2>(Bw, bcol, H_, 0, vb);
  rs_write<128, 32, 2>(As[0], va);
  rs_write<128, 32, 2>(Bs[0], vb);
  __syncthreads();
  int cur = 0;
  for (int c = 0; c < 16; ++c) {
    if (c < 15) {
      rs_load<128, 32, 2>(A, arow, H_, (c + 1) * 32, va);
      rs_load<128, 32, 2>(Bw, bcol, H_, (c + 1) * 32, vb);
    }
    bf16x8 af[4], bf[4];
#pragma unroll
    for (int i = 0; i < 4; ++i) af[i] = fragL<32>(As[cur], wm * 64 + i * 16 + r, ko);
#pragma unroll
    for (int j = 0; j < 4; ++j) bf[j] = fragL<32>(Bs[cur], wn * 64 + j * 16 + r, ko);
#pragma unroll
    for (int i = 0; i < 4; ++i)
#pragma unroll
      for (int j = 0; j < 4; ++j)
        acc[i][j] = __builtin_amdgcn_mfma_f32_16x16x32_bf16(af[i], bf[j], acc[i][j], 0, 0, 0);
    if (c < 15) {
      rs_write<128, 32, 2>(As[cur ^ 1], va);
      rs_write<128, 32, 2>(Bs[cur ^ 1], vb);
    }
    __syncthreads();
    cur ^= 1;
  }
}

// ======== shared arg bundle ========
struct GArgs {
  const short* zgx; const short* egx; const int* target;
  float* h0f; float* h1f; short* h0b; short* h1b;
  short* p0;                    // [2048][4][512] bf16: sr, sz, xn, hn
  short* gx1; short* gh1;       // [2048][1536]
  const short* Wb_hh0; const float* b_hh0;
  const short* Wb_ih1; const float* b_ih1;
  const short* Wb_hh1; const float* b_hh1;
  const short* Wb_out; const float* fc_out_b;
  float* out;
};

// ============ L1(t): G0(t)->p0 | X1(t-1)->gx1 | G1(t-1)->gh1 | LG(t-2) logits ============
// u<576: grp=u/36 (128-row m-tile), rem=u%36: [0,12) G0, [12,24) X1, [24,36) G1.
// u in [576,704): LG 16-row logits bands.
__global__ __launch_bounds__(256, 3) void k_L1(GArgs a, int t) {
  extern __shared__ char smem[];
  const int u = blockIdx.x;
  const int tid = threadIdx.x, lane = tid & 63, wid = tid >> 6;
  const int wm = wid >> 1, wn = wid & 1;
  const int r0 = (lane >> 4) * 4, c0 = lane & 15, ko = (lane >> 4) * 8;
  if (u < 576) {
    const int grp = u / 36, rem = u % 36;
    const int arow = grp * 128;
    if (rem < 12) {
      // ---- G0(t): gh0 GEMM + pack epilogue (fold zgx+egx once)
      if (t >= T_) return;
      const int bcol = rem * 128;
      f32x4 acc[4][4] = {};
      gemm128(a.h0b, a.Wb_hh0, arow, bcol, smem, acc);
      const int g = rem >> 2;  // gate of this 128-col tile
#pragma unroll
      for (int i = 0; i < 4; ++i)
#pragma unroll
        for (int j = 0; j < 4; ++j) {
          const int col = bcol + wn * 64 + j * 16 + c0;
          const int jj = col & 511;
          const float bv = a.b_hh0[col];
#pragma unroll
          for (int rr = 0; rr < 4; ++rr) {
            const int row = arow + wm * 64 + i * 16 + r0 + rr;
            const float val = acc[i][j][rr] + bv;  // h-side gate pre-act
            const int tok = (t == 0) ? 1 : a.target[(size_t)row * T_ + (t - 1)];
            const float xv = b2f(a.zgx[(size_t)row * H3 + g * 512 + jj]) +
                             b2f(a.egx[(size_t)tok * H3 + g * 512 + jj]);
            short* pr = a.p0 + ((size_t)row * 4) * 512 + jj;
            if (g < 2) {
              pr[g * 512] = f2b(val + xv);        // sr or sz
            } else {
              pr[2 * 512] = f2b(xv);              // xn
              pr[3 * 512] = f2b(val);             // hn
            }
          }
        }
    } else if (rem < 24) {
      // ---- X1(t-1): gx1 GEMM
      if (t < 1 || t > T_) return;
      const int bcol = (rem - 12) * 128;
      f32x4 acc[4][4] = {};
      gemm128(a.h0b, a.Wb_ih1, arow, bcol, smem, acc);
#pragma unroll
      for (int i = 0; i < 4; ++i)
#pragma unroll
        for (int j = 0; j < 4; ++j) {
          const int col = bcol + wn * 64 + j * 16 + c0;
          const float bv = a.b_ih1[col];
#pragma unroll
          for (int rr = 0; rr < 4; ++rr)
            a.gx1[(size_t)(arow + wm * 64 + i * 16 + r0 + rr) * H3 + col] =
                f2b(acc[i][j][rr] + bv);
        }
    } else {
      // ---- G1(t-1): gh1 GEMM
      if (t < 1 || t > T_) return;
      const int bcol = (rem - 24) * 128;
      f32x4 acc[4][4] = {};
      gemm128(a.h1b, a.Wb_hh1, arow, bcol, smem, acc);
#pragma unroll
      for (int i = 0; i < 4; ++i)
#pragma unroll
        for (int j = 0; j < 4; ++j) {
          const int col = bcol + wn * 64 + j * 16 + c0;
          const float bv = a.b_hh1[col];
#pragma unroll
          for (int rr = 0; rr < 4; ++rr)
            a.gh1[(size_t)(arow + wm * 64 + i * 16 + r0 + rr) * H3 + col] =
                f2b(acc[i][j][rr] + bv);
        }
    }
    return;
  }
  // ---- LG(t-2): logits for step t-2, 16-row band; reads h1b (= h1(t-2))
  if (t < 2) return;
  const int row0 = (u - 576) * 16;
  const int tlog = t - 2;
  const int w = wid;
  f32x4 acc = {};
  const short* ap = a.h1b + (size_t)(row0 + c0) * H_ + ko;
  const short* wp = a.Wb_out + (size_t)(w * 16 + c0) * H_ + ko;
#pragma unroll
  for (int m = 0; m < 16; ++m) {
    bf16x8 av = *(const bf16x8*)(ap + m * 32);
    bf16x8 bw = *(const bf16x8*)(wp + m * 32);
    acc = __builtin_amdgcn_mfma_f32_16x16x32_bf16(av, bw, acc, 0, 0, 0);
  }
  const float bv = a.fc_out_b[w * 16 + c0];
#pragma unroll
  for (int rr = 0; rr < 4; ++rr)
    a.out[((size_t)(row0 + r0 + rr) * T_ + tlog) * V_ + w * 16 + c0] = acc[rr] + bv;
}

// ================= L2(t): Dp(t) pw0 | P1h(t-1) pw1 (pure elementwise) =================
__global__ __launch_bounds__(256) void k_L2(GArgs a, int t) {
  const int u = blockIdx.x;
  const int tid = threadIdx.x;
  if (u < 64) {
    // ---- Dp(t): pw0, 32-row band (reads p0, updates h0f/h0b)
    if (t >= T_) return;
    const int row0 = u * 32;
#pragma unroll 1
    for (int it = 0; it < 8; ++it) {
      int v = it * 256 + tid;
      int rl = v >> 6, jb = v & 63;
      int row = row0 + rl, j = jb * 8;
      const short* pr = a.p0 + ((size_t)row * 4) * 512 + j;
      bf16x8 sr = *(const bf16x8*)(pr);
      bf16x8 sz = *(const bf16x8*)(pr + 512);
      bf16x8 xn = *(const bf16x8*)(pr + 1024);
      bf16x8 hn = *(const bf16x8*)(pr + 1536);
      float* hf = a.h0f + (size_t)row * H_ + j;
      float4 hp0 = *(const float4*)(hf);
      float4 hp1 = *(const float4*)(hf + 4);
      float hp[8] = {hp0.x, hp0.y, hp0.z, hp0.w, hp1.x, hp1.y, hp1.z, hp1.w};
      float hv[8];
      bf16x8 ov;
#pragma unroll
      for (int e = 0; e < 8; ++e) {
        hv[e] = gru_pre(b2f(sr[e]), b2f(sz[e]), b2f(xn[e]), b2f(hn[e]), hp[e]);
        ov[e] = f2b(hv[e]);
      }
      *(float4*)(hf) = make_float4(hv[0], hv[1], hv[2], hv[3]);
      *(float4*)(hf + 4) = make_float4(hv[4], hv[5], hv[6], hv[7]);
      *(bf16x8*)(a.h0b + (size_t)row * H_ + j) = ov;
    }
    return;
  }
  // ---- P1h(t-1): pw1, 32-row band (reads gx1/gh1, updates h1f/h1b)
  if (t < 1 || t > T_) return;
  const int row0 = (u - 64) * 32;
#pragma unroll 1
  for (int it = 0; it < 8; ++it) {
    int v = it * 256 + tid;
    int rl = v >> 6, jb = v & 63;
    int row = row0 + rl, j = jb * 8;
    const short* gx = a.gx1 + (size_t)row * H3 + j;
    const short* gh = a.gh1 + (size_t)row * H3 + j;
    float* hf = a.h1f + (size_t)row * H_ + j;
    bf16x8 xr = *(const bf16x8*)(gx);
    bf16x8 xz = *(const bf16x8*)(gx + H_);
    bf16x8 xn = *(const bf16x8*)(gx + 2 * H_);
    bf16x8 hr = *(const bf16x8*)(gh);
    bf16x8 hz = *(const bf16x8*)(gh + H_);
    bf16x8 hn = *(const bf16x8*)(gh + 2 * H_);
    float4 hp0 = *(const float4*)(hf);
    float4 hp1 = *(const float4*)(hf + 4);
    float hp[8] = {hp0.x, hp0.y, hp0.z, hp0.w, hp1.x, hp1.y, hp1.z, hp1.w};
    float hv[8];
    bf16x8 ov;
#pragma unroll
    for (int e = 0; e < 8; ++e) {
      hv[e] = gru_one(b2f(xr[e]), b2f(xz[e]), b2f(xn[e]),
                      b2f(hr[e]), b2f(hz[e]), b2f(hn[e]), hp[e]);
      ov[e] = f2b(hv[e]);
    }
    *(float4*)(hf) = make_float4(hv[0], hv[1], hv[2], hv[3]);
    *(float4*)(hf + 4) = make_float4(hv[4], hv[5], hv[6], hv[7]);
    *(bf16x8*)(a.h1b + (size_t)row * H_ + j) = ov;
  }
}

// ================= prep kernels =================
template <int MI, int NJ>
DI void gemm_wave_global(const short* __restrict__ A, const short* __restrict__ B,
                         const int K, const int arow, const int bcol,
                         f32x4 (&acc)[MI][NJ]) {
  const int lane = threadIdx.x & 63;
  const int r = lane & 15, ko = (lane >> 4) * 8;
  const short* Ap = A + (size_t)(arow + r) * K + ko;
  const short* Bp = B + (size_t)(bcol + r) * K + ko;
  for (int kk = 0; kk < K; kk += 32) {
    bf16x8 a[MI], b[NJ];
#pragma unroll
    for (int i = 0; i < MI; ++i) a[i] = *(const bf16x8*)(Ap + (size_t)i * 16 * K + kk);
#pragma unroll
    for (int j = 0; j < NJ; ++j) b[j] = *(const bf16x8*)(Bp + (size_t)j * 16 * K + kk);
#pragma unroll
    for (int i = 0; i < MI; ++i)
#pragma unroll
      for (int j = 0; j < NJ; ++j)
        acc[i][j] = __builtin_amdgcn_mfma_f32_16x16x32_bf16(a[i], b[j], acc[i][j], 0, 0, 0);
  }
}
template <int MI, int NJ>
DI void epi_store_bf16(short* __restrict__ C, const float* __restrict__ bias,
                       const int N, const int arow, const int bcol, f32x4 (&acc)[MI][NJ]) {
  const int lane = threadIdx.x & 63;
  const int r0 = (lane >> 4) * 4, c0 = lane & 15;
#pragma unroll
  for (int i = 0; i < MI; ++i)
#pragma unroll
    for (int j = 0; j < NJ; ++j) {
      int col = bcol + j * 16 + c0;
      float bv = bias[col];
#pragma unroll
      for (int rr = 0; rr < 4; ++rr)
        C[(size_t)(arow + i * 16 + r0 + rr) * N + col] = f2b(acc[i][j][rr] + bv);
    }
}

__global__ __launch_bounds__(256) void k_prep0(
    const float* __restrict__ W_hh0, const float* __restrict__ W_ih1,
    const float* __restrict__ W_hh1, const float* __restrict__ fc_out_w,
    const float* __restrict__ W_ih0, const float* __restrict__ fc_hidden_w,
    const float* __restrict__ z,
    short* Wb_hh0, short* Wb_ih1, short* Wb_hh1, short* Wb_out,
    short* Wb_ih0z, short* Wb_fch, short* z_b) {
  const int n1 = H3 * H_;
  const int n2 = V_ * H_;
  const int n3 = H3 * LAT_;
  const int n4 = (2 * H_) * LAT_;
  const int n5 = B_ * LAT_;
  const int total = n1 * 3 + n2 + n3 + n4 + n5;
  for (int i = blockIdx.x * blockDim.x + threadIdx.x; i < total;
       i += gridDim.x * blockDim.x) {
    int idx = i;
    if (idx < n1) { Wb_hh0[idx] = f2b(W_hh0[idx]); continue; }
    idx -= n1;
    if (idx < n1) { Wb_ih1[idx] = f2b(W_ih1[idx]); continue; }
    idx -= n1;
    if (idx < n1) { Wb_hh1[idx] = f2b(W_hh1[idx]); continue; }
    idx -= n1;
    if (idx < n2) { Wb_out[idx] = f2b(fc_out_w[idx]); continue; }
    idx -= n2;
    if (idx < n3) {
      int n = idx >> 8, k = idx & 255;
      Wb_ih0z[idx] = f2b(W_ih0[(size_t)n * (E_ + LAT_) + E_ + k]);
      continue;
    }
    idx -= n3;
    if (idx < n4) { Wb_fch[idx] = f2b(fc_hidden_w[idx]); continue; }
    idx -= n4;
    z_b[idx] = f2b(z[idx]);
  }
}

__global__ __launch_bounds__(256) void k_prep_emb(const float* __restrict__ embed,
                                                  const float* __restrict__ W_ih0,
                                                  short* __restrict__ egx) {
  __shared__ float er[E_];
  int v = blockIdx.x;
  for (int e = threadIdx.x; e < E_; e += blockDim.x) er[e] = embed[(size_t)v * E_ + e];
  __syncthreads();
  for (int n = threadIdx.x; n < H3; n += blockDim.x) {
    const float* w = W_ih0 + (size_t)n * (E_ + LAT_);
    float acc = 0.f;
#pragma unroll 8
    for (int e = 0; e < E_; ++e) acc += er[e] * w[e];
    egx[(size_t)v * H3 + n] = f2b(acc);
  }
}

__global__ __launch_bounds__(256) void k_prep1(
    const short* __restrict__ z_b, const short* __restrict__ Wb_ih0z,
    const short* __restrict__ Wb_fch, const float* __restrict__ b_ih0,
    const float* __restrict__ fc_hidden_b,
    short* zgx, float* h0f, float* h1f, short* h0b, short* h1b) {
  const int bid = blockIdx.x;
  const int mtile = bid / 20, ntile = bid % 20;
  const int tid = threadIdx.x, lane = tid & 63, wid = tid >> 6;
  const int wm = wid >> 1, wn = wid & 1;
  const int arow = mtile * 128 + wm * 64;
  f32x4 acc[4][4] = {};
  if (ntile < 12) {
    int bcol = ntile * 128 + wn * 64;
    gemm_wave_global<4, 4>(z_b, Wb_ih0z, LAT_, arow, bcol, acc);
    epi_store_bf16<4, 4>(zgx, b_ih0, H3, arow, bcol, acc);
  } else {
    int bcol = (ntile - 12) * 128 + wn * 64;
    gemm_wave_global<4, 4>(z_b, Wb_fch, LAT_, arow, bcol, acc);
    const int r0 = (lane >> 4) * 4, c0 = lane & 15;
#pragma unroll
    for (int i = 0; i < 4; ++i)
#pragma unroll
      for (int j = 0; j < 4; ++j) {
        int col = bcol + j * 16 + c0;
        float bv = fc_hidden_b[col];
#pragma unroll
        for (int rr = 0; rr < 4; ++rr) {
          int row = arow + i * 16 + r0 + rr;
          float v = acc[i][j][rr] + bv;
          if (col < H_) {
            h0f[(size_t)row * H_ + col] = v;
            h0b[(size_t)row * H_ + col] = f2b(v);
          } else {
            h1f[(size_t)row * H_ + (col - H_)] = v;
            h1b[(size_t)row * H_ + (col - H_)] = f2b(v);
          }
        }
      }
  }
}

extern "C" void kernel_launch(void* const* d_in, const int* in_sizes, int n_in,
                              void* d_out, int out_size, void* d_ws, size_t ws_size,
                              hipStream_t stream) {
  const float* z           = (const float*)d_in[0];
  const int*   target      = (const int*)d_in[1];
  const float* embed       = (const float*)d_in[2];
  const float* fc_hidden_w = (const float*)d_in[3];
  const float* fc_hidden_b = (const float*)d_in[4];
  const float* W_ih0       = (const float*)d_in[5];
  const float* W_hh0       = (const float*)d_in[6];
  const float* b_ih0       = (const float*)d_in[7];
  const float* b_hh0       = (const float*)d_in[8];
  const float* W_ih1       = (const float*)d_in[9];
  const float* W_hh1       = (const float*)d_in[10];
  const float* b_ih1       = (const float*)d_in[11];
  const float* b_hh1       = (const float*)d_in[12];
  const float* fc_out_w    = (const float*)d_in[13];
  const float* fc_out_b    = (const float*)d_in[14];
  float* out = (float*)d_out;

  char* ws = (char*)d_ws;
  size_t off = 0;
  auto alloc = [&](size_t bytes) -> void* {
    off = (off + 255) & ~(size_t)255;
    void* p = ws + off;
    off += bytes;
    return p;
  };
  float* h0f    = (float*)alloc((size_t)B_ * H_ * 4);
  float* h1f    = (float*)alloc((size_t)B_ * H_ * 4);
  short* h0b    = (short*)alloc((size_t)B_ * H_ * 2);
  short* h1b    = (short*)alloc((size_t)B_ * H_ * 2);
  short* p0     = (short*)alloc((size_t)B_ * 4 * H_ * 2);
  short* gx1    = (short*)alloc((size_t)B_ * H3 * 2);
  short* gh1    = (short*)alloc((size_t)B_ * H3 * 2);
  short* zgx    = (short*)alloc((size_t)B_ * H3 * 2);
  short* egx    = (short*)alloc((size_t)V_ * H3 * 2);
  short* Wb_hh0 = (short*)alloc((size_t)H3 * H_ * 2);
  short* Wb_ih1 = (short*)alloc((size_t)H3 * H_ * 2);
  short* Wb_hh1 = (short*)alloc((size_t)H3 * H_ * 2);
  short* Wb_out = (short*)alloc((size_t)V_ * H_ * 2);
  short* Wb_ih0z= (short*)alloc((size_t)H3 * LAT_ * 2);
  short* Wb_fch = (short*)alloc((size_t)2 * H_ * LAT_ * 2);
  short* z_b    = (short*)alloc((size_t)B_ * LAT_ * 2);
  if (off > ws_size) return;

  k_prep0<<<2048, 256, 0, stream>>>(W_hh0, W_ih1, W_hh1, fc_out_w, W_ih0, fc_hidden_w,
                                    z, Wb_hh0, Wb_ih1, Wb_hh1, Wb_out, Wb_ih0z, Wb_fch, z_b);
  k_prep_emb<<<64, 256, 0, stream>>>(embed, W_ih0, egx);
  k_prep1<<<320, 256, 0, stream>>>(z_b, Wb_ih0z, Wb_fch, b_ih0, fc_hidden_b,
                                   zgx, h0f, h1f, h0b, h1b);

  GArgs a;
  a.zgx = zgx; a.egx = egx; a.target = target;
  a.h0f = h0f; a.h1f = h1f; a.h0b = h0b; a.h1b = h1b;
  a.p0 = p0; a.gx1 = gx1; a.gh1 = gh1;
  a.Wb_hh0 = Wb_hh0; a.b_hh0 = b_hh0;
  a.Wb_ih1 = Wb_ih1; a.b_ih1 = b_ih1;
  a.Wb_hh1 = Wb_hh1; a.b_hh1 = b_hh1;
  a.Wb_out = Wb_out; a.fc_out_b = fc_out_b;
  a.out = out;

  // Skewed 2-launch pipeline, single residency round per launch:
  //   L1(t): G0(t)->p0 | X1(t-1)->gx1 | G1(t-1)->gh1 | LG(t-2) logits
  //   L2(t): Dp(t): pw0 -> h0 | P1h(t-1): pw1 -> h1
  for (int t = 0; t <= T_ + 1; ++t) {
    k_L1<<<704, 256, 32768, stream>>>(a, t);
    if (t <= T_) k_L2<<<128, 256, 0, stream>>>(a, t);
  }
}

// Round 10
// 4424.003 us; speedup vs baseline: 1.7065x; 1.7065x over previous
//
#include <hip/hip_runtime.h>
#include <hip/hip_bf16.h>

#define DI __device__ __forceinline__

typedef short bf16x8 __attribute__((ext_vector_type(8)));
typedef float f32x4 __attribute__((ext_vector_type(4)));

constexpr int B_ = 2048, T_ = 120, V_ = 64, E_ = 128, H_ = 512, LAT_ = 256;
constexpr int H3 = 1536;  // 3*H

DI short f2b(float f) {
  union { __hip_bfloat16 h; short s; } u;
  u.h = __float2bfloat16(f);
  return u.s;
}
DI float b2f(short s) {
  union { unsigned u; float f; } x;
  x.u = (unsigned)(unsigned short)s << 16;
  return x.f;
}
DI float sigm(float x) { return 1.f / (1.f + __expf(-x)); }
DI float tanh_f(float x) {
  x = fminf(15.f, fmaxf(-15.f, x));
  float e = __expf(2.f * x);
  return (e - 1.f) / (e + 1.f);
}
DI float gru_one(float xr, float xz, float xn, float hr, float hz, float hn, float hp) {
  float r = sigm(xr + hr);
  float u = sigm(xz + hz);
  float nn = tanh_f(xn + r * hn);
  return (1.f - u) * nn + u * hp;
}
// pre-summed form: sr = xr+hr, sz = xz+hz; xn, hn separate
DI float gru_pre(float sr, float sz, float xn, float hn, float hp) {
  float r = sigm(sr);
  float u = sigm(sz);
  float nn = tanh_f(xn + r * hn);
  return (1.f - u) * nn + u * hp;
}

// XCD-locality mapping: units v and v+1 (same weight slice) land on the same XCD,
// assuming blockIdx round-robins XCDs (bid % 8). Bijective on [0, nunits) for
// nunits % 8 == 0, so at worst it's a harmless permutation.
template <int NUNITS>
DI int xcd_map(int u) {
  constexpr int PER = NUNITS / 8;
  return (u % 8) * PER + u / 8;
}

// ======== register staging: global -> regs -> swizzled ds_write (256 threads) ========
template <int ROWS, int BK, int NV>
DI void rs_load(const short* __restrict__ G, int row0, int K, int kk, bf16x8 (&v)[NV]) {
  constexpr int SLOTS = BK / 8;
  constexpr int RPP = 2048 / BK;
  static_assert(NV == ROWS / RPP, "NV mismatch");
  const int tid = threadIdx.x;
  const int rl = tid / SLOTS, sl = tid % SLOTS;
#pragma unroll
  for (int p = 0; p < NV; ++p)
    v[p] = *(const bf16x8*)(G + (size_t)(row0 + p * RPP + rl) * K + kk + sl * 8);
}
template <int ROWS, int BK, int NV>
DI void rs_write(char* __restrict__ lds, bf16x8 (&v)[NV]) {
  constexpr int SLOTS = BK / 8;
  constexpr int RPP = 2048 / BK;
  const int tid = threadIdx.x;
  const int rl = tid / SLOTS, sl = tid % SLOTS;
#pragma unroll
  for (int p = 0; p < NV; ++p) {
    int row = p * RPP + rl;
    *(bf16x8*)(lds + row * (SLOTS * 16) + ((sl ^ (row & (SLOTS - 1))) * 16)) = v[p];
  }
}
template <int BK>
DI bf16x8 fragL(const char* __restrict__ lds, int row, int kk) {
  return *(const bf16x8*)(lds + row * (BK * 2) + ((kk << 1) ^ ((row & (BK / 8 - 1)) << 4)));
}

// ======== core 64x128 GEMM: acc = A[64x512] @ W[128x512]^T, BK=64 dbuf LDS (48KB) ========
DI void gemm_core(const short* __restrict__ A, const short* __restrict__ Bw,
                  int arow, int bcol, char* lds, f32x4 (&acc)[2][4]) {
  char* As[2] = {lds, lds + 8192};
  char* Bs[2] = {lds + 16384, lds + 32768};
  const int tid = threadIdx.x, lane = tid & 63, wid = tid >> 6;
  const int wm = wid >> 1, wn = wid & 1;
  const int r = lane & 15, ko = (lane >> 4) * 8;
  bf16x8 va[2], vb[4];
  rs_load<64, 64, 2>(A, arow, H_, 0, va);
  rs_load<128, 64, 4>(Bw, bcol, H_, 0, vb);
  rs_write<64, 64, 2>(As[0], va);
  rs_write<128, 64, 4>(Bs[0], vb);
  __syncthreads();
  int cur = 0;
  for (int c = 0; c < 8; ++c) {
    if (c < 7) {
      rs_load<64, 64, 2>(A, arow, H_, (c + 1) * 64, va);
      rs_load<128, 64, 4>(Bw, bcol, H_, (c + 1) * 64, vb);
    }
#pragma unroll
    for (int kh = 0; kh < 2; ++kh) {
      const int kkk = kh * 32 + ko;
      bf16x8 a[2], b[4];
#pragma unroll
      for (int i = 0; i < 2; ++i) a[i] = fragL<64>(As[cur], wm * 32 + i * 16 + r, kkk);
#pragma unroll
      for (int j = 0; j < 4; ++j) b[j] = fragL<64>(Bs[cur], wn * 64 + j * 16 + r, kkk);
#pragma unroll
      for (int i = 0; i < 2; ++i)
#pragma unroll
        for (int j = 0; j < 4; ++j)
          acc[i][j] = __builtin_amdgcn_mfma_f32_16x16x32_bf16(a[i], b[j], acc[i][j], 0, 0, 0);
    }
    if (c < 7) {
      rs_write<64, 64, 2>(As[cur ^ 1], va);
      rs_write<128, 64, 4>(Bs[cur ^ 1], vb);
    }
    __syncthreads();
    cur ^= 1;
  }
}

// ======== shared arg bundle ========
struct GArgs {
  const short* zgx; const short* egx; const int* target;
  float* h0f; float* h1f; short* h0b; short* h1b;
  short* p0;                    // [2048][4][512] bf16: sr, sz, xn, hn
  short* gx1a; short* gx1b;     // ping-pong [2048][1536]
  short* gh1;                   // [2048][1536]
  const short* Wb_hh0; const float* b_hh0;
  const short* Wb_ih1; const float* b_ih1;
  const short* Wb_hh1; const float* b_hh1;
  const short* Wb_out; const float* fc_out_b;
  float* out;
};

// ================= A(t): G0(t) -> p0 | X1(t-1) -> gx1 | P1(t-2)+logits =================
__global__ __launch_bounds__(256) void k_A(GArgs a, int t) {
  extern __shared__ char smem[];
  const int u = blockIdx.x;
  const int tid = threadIdx.x, lane = tid & 63, wid = tid >> 6;
  if (u < 384) {
    // ---- G0(t): gh0 GEMM, pack epilogue (XCD-grouped by weight slice)
    if (t >= T_) return;
    const int v = xcd_map<384>(u);
    const int nt = v / 32, mt = v % 32;
    const int arow = mt * 64, bcol = nt * 128;
    f32x4 acc[2][4] = {};
    gemm_core(a.h0b, a.Wb_hh0, arow, bcol, smem, acc);
    const int wm = wid >> 1, wn = wid & 1;
    const int r0 = (lane >> 4) * 4, c0 = lane & 15;
    const int g = nt >> 2;  // whole 128-col tile lies in one gate
#pragma unroll
    for (int i = 0; i < 2; ++i)
#pragma unroll
      for (int j = 0; j < 4; ++j) {
        const int col = bcol + wn * 64 + j * 16 + c0;
        const int jj = col & 511;
        const float bv = a.b_hh0[col];
#pragma unroll
        for (int rr = 0; rr < 4; ++rr) {
          const int row = arow + wm * 32 + i * 16 + r0 + rr;
          const float val = acc[i][j][rr] + bv;  // h-side gate pre-act
          const int tok = (t == 0) ? 1 : a.target[(size_t)row * T_ + (t - 1)];
          const float xv = b2f(a.zgx[(size_t)row * H3 + g * 512 + jj]) +
                           b2f(a.egx[(size_t)tok * H3 + g * 512 + jj]);
          short* pr = a.p0 + ((size_t)row * 4) * 512 + jj;
          if (g < 2) {
            pr[g * 512] = f2b(val + xv);        // sr or sz
          } else {
            pr[2 * 512] = f2b(xv);              // xn
            pr[3 * 512] = f2b(val);             // hn
          }
        }
      }
    return;
  }
  if (u < 768) {
    // ---- X1(t-1): gx1 GEMM (XCD-grouped)
    if (t < 1 || t > T_) return;
    short* gxw = ((t - 1) & 1) ? a.gx1b : a.gx1a;
    const int v = xcd_map<384>(u - 384);
    const int nt = v / 32, mt = v % 32;
    const int arow = mt * 64, bcol = nt * 128;
    f32x4 acc[2][4] = {};
    gemm_core(a.h0b, a.Wb_ih1, arow, bcol, smem, acc);
    const int wm = wid >> 1, wn = wid & 1;
    const int r0 = (lane >> 4) * 4, c0 = lane & 15;
#pragma unroll
    for (int i = 0; i < 2; ++i)
#pragma unroll
      for (int j = 0; j < 4; ++j) {
        const int col = bcol + wn * 64 + j * 16 + c0;
        const float bv = a.b_ih1[col];
#pragma unroll
        for (int rr = 0; rr < 4; ++rr)
          gxw[(size_t)(arow + wm * 32 + i * 16 + r0 + rr) * H3 + col] = f2b(acc[i][j][rr] + bv);
      }
    return;
  }
  // ---- P1(t-2) + logits(t-2): 16-row band
  if (t < 2) return;
  const short* gxr = (t & 1) ? a.gx1b : a.gx1a;  // (t-2)&1 == t&1
  short* sh = (short*)smem;
  const int row0 = (u - 768) * 16;
  const int tlog = t - 2;
#pragma unroll 1
  for (int c = 0; c < 4; ++c) {
    int f = c * 2048 + tid * 8;
    int rl = f >> 9, j = f & 511;
    int row = row0 + rl;
    const short* gx = gxr + (size_t)row * H3 + j;
    const short* gh = a.gh1 + (size_t)row * H3 + j;
    float* hf = a.h1f + (size_t)row * H_ + j;
    bf16x8 xr = *(const bf16x8*)(gx);
    bf16x8 xz = *(const bf16x8*)(gx + H_);
    bf16x8 xn = *(const bf16x8*)(gx + 2 * H_);
    bf16x8 hr = *(const bf16x8*)(gh);
    bf16x8 hz = *(const bf16x8*)(gh + H_);
    bf16x8 hn = *(const bf16x8*)(gh + 2 * H_);
    float4 hp0 = *(const float4*)(hf);
    float4 hp1 = *(const float4*)(hf + 4);
    float hp[8] = {hp0.x, hp0.y, hp0.z, hp0.w, hp1.x, hp1.y, hp1.z, hp1.w};
    float hv[8];
    bf16x8 ov;
#pragma unroll
    for (int e = 0; e < 8; ++e) {
      hv[e] = gru_one(b2f(xr[e]), b2f(xz[e]), b2f(xn[e]),
                      b2f(hr[e]), b2f(hz[e]), b2f(hn[e]), hp[e]);
      ov[e] = f2b(hv[e]);
    }
    *(float4*)(hf) = make_float4(hv[0], hv[1], hv[2], hv[3]);
    *(float4*)(hf + 4) = make_float4(hv[4], hv[5], hv[6], hv[7]);
    *(bf16x8*)(a.h1b + (size_t)row * H_ + j) = ov;
    *(bf16x8*)(&sh[rl * 520 + j]) = ov;
  }
  __syncthreads();
  const int w = tid >> 6;
  const int c0 = lane & 15, ko = (lane >> 4) * 8;
  f32x4 acc = {};
  const short* wb = a.Wb_out + (size_t)(w * 16 + c0) * H_ + ko;
  const short* ap = &sh[c0 * 520 + ko];
#pragma unroll
  for (int m = 0; m < 16; ++m) {
    bf16x8 av = *(const bf16x8*)(ap + m * 32);
    bf16x8 bw = *(const bf16x8*)(wb + m * 32);
    acc = __builtin_amdgcn_mfma_f32_16x16x32_bf16(av, bw, acc, 0, 0, 0);
  }
  const int r0 = (lane >> 4) * 4;
  const int col = w * 16 + c0;
  const float bv = a.fc_out_b[col];
#pragma unroll
  for (int rr = 0; rr < 4; ++rr) {
    int brow = row0 + r0 + rr;
    a.out[((size_t)brow * T_ + tlog) * V_ + col] = acc[rr] + bv;
  }
}

// ================= C(t): Dp(t) pw0 | G1(t-1) gh1 GEMM =================
__global__ __launch_bounds__(256) void k_C(GArgs a, int t) {
  extern __shared__ char smem[];
  const int u = blockIdx.x;
  const int tid = threadIdx.x;
  if (u < 128) {
    // ---- Dp(t): pw0 elementwise on 16-row band (reads p0, updates h0f/h0b)
    if (t >= T_) return;
    const int row0 = u * 16;
#pragma unroll 1
    for (int it = 0; it < 4; ++it) {
      int v = it * 256 + tid;       // 1024 vec8-units per block
      int rl = v >> 6, jb = v & 63;
      int row = row0 + rl, j = jb * 8;
      const short* pr = a.p0 + ((size_t)row * 4) * 512 + j;
      bf16x8 sr = *(const bf16x8*)(pr);
      bf16x8 sz = *(const bf16x8*)(pr + 512);
      bf16x8 xn = *(const bf16x8*)(pr + 1024);
      bf16x8 hn = *(const bf16x8*)(pr + 1536);
      float* hf = a.h0f + (size_t)row * H_ + j;
      float4 hp0 = *(const float4*)(hf);
      float4 hp1 = *(const float4*)(hf + 4);
      float hp[8] = {hp0.x, hp0.y, hp0.z, hp0.w, hp1.x, hp1.y, hp1.z, hp1.w};
      float hv[8];
      bf16x8 ov;
#pragma unroll
      for (int e = 0; e < 8; ++e) {
        hv[e] = gru_pre(b2f(sr[e]), b2f(sz[e]), b2f(xn[e]), b2f(hn[e]), hp[e]);
        ov[e] = f2b(hv[e]);
      }
      *(float4*)(hf) = make_float4(hv[0], hv[1], hv[2], hv[3]);
      *(float4*)(hf + 4) = make_float4(hv[4], hv[5], hv[6], hv[7]);
      *(bf16x8*)(a.h0b + (size_t)row * H_ + j) = ov;
    }
    return;
  }
  // ---- G1(t-1): gh1 GEMM (XCD-grouped)
  if (t < 1 || t > T_) return;
  const int v = xcd_map<384>(u - 128);
  const int nt = v / 32, mt = v % 32;
  const int arow = mt * 64, bcol = nt * 128;
  f32x4 acc[2][4] = {};
  gemm_core(a.h1b, a.Wb_hh1, arow, bcol, smem, acc);
  const int lane = tid & 63, wid = tid >> 6;
  const int wm = wid >> 1, wn = wid & 1;
  const int r0 = (lane >> 4) * 4, c0 = lane & 15;
#pragma unroll
  for (int i = 0; i < 2; ++i)
#pragma unroll
    for (int j = 0; j < 4; ++j) {
      const int col = bcol + wn * 64 + j * 16 + c0;
      const float bv = a.b_hh1[col];
#pragma unroll
      for (int rr = 0; rr < 4; ++rr)
        a.gh1[(size_t)(arow + wm * 32 + i * 16 + r0 + rr) * H3 + col] = f2b(acc[i][j][rr] + bv);
    }
}

// ================= prep kernels =================
template <int MI, int NJ>
DI void gemm_wave_global(const short* __restrict__ A, const short* __restrict__ B,
                         const int K, const int arow, const int bcol,
                         f32x4 (&acc)[MI][NJ]) {
  const int lane = threadIdx.x & 63;
  const int r = lane & 15, ko = (lane >> 4) * 8;
  const short* Ap = A + (size_t)(arow + r) * K + ko;
  const short* Bp = B + (size_t)(bcol + r) * K + ko;
  for (int kk = 0; kk < K; kk += 32) {
    bf16x8 a[MI], b[NJ];
#pragma unroll
    for (int i = 0; i < MI; ++i) a[i] = *(const bf16x8*)(Ap + (size_t)i * 16 * K + kk);
#pragma unroll
    for (int j = 0; j < NJ; ++j) b[j] = *(const bf16x8*)(Bp + (size_t)j * 16 * K + kk);
#pragma unroll
    for (int i = 0; i < MI; ++i)
#pragma unroll
      for (int j = 0; j < NJ; ++j)
        acc[i][j] = __builtin_amdgcn_mfma_f32_16x16x32_bf16(a[i], b[j], acc[i][j], 0, 0, 0);
  }
}
template <int MI, int NJ>
DI void epi_store_bf16(short* __restrict__ C, const float* __restrict__ bias,
                       const int N, const int arow, const int bcol, f32x4 (&acc)[MI][NJ]) {
  const int lane = threadIdx.x & 63;
  const int r0 = (lane >> 4) * 4, c0 = lane & 15;
#pragma unroll
  for (int i = 0; i < MI; ++i)
#pragma unroll
    for (int j = 0; j < NJ; ++j) {
      int col = bcol + j * 16 + c0;
      float bv = bias[col];
#pragma unroll
      for (int rr = 0; rr < 4; ++rr)
        C[(size_t)(arow + i * 16 + r0 + rr) * N + col] = f2b(acc[i][j][rr] + bv);
    }
}

__global__ __launch_bounds__(256) void k_prep0(
    const float* __restrict__ W_hh0, const float* __restrict__ W_ih1,
    const float* __restrict__ W_hh1, const float* __restrict__ fc_out_w,
    const float* __restrict__ W_ih0, const float* __restrict__ fc_hidden_w,
    const float* __restrict__ z,
    short* Wb_hh0, short* Wb_ih1, short* Wb_hh1, short* Wb_out,
    short* Wb_ih0z, short* Wb_fch, short* z_b) {
  const int n1 = H3 * H_;
  const int n2 = V_ * H_;
  const int n3 = H3 * LAT_;
  const int n4 = (2 * H_) * LAT_;
  const int n5 = B_ * LAT_;
  const int total = n1 * 3 + n2 + n3 + n4 + n5;
  for (int i = blockIdx.x * blockDim.x + threadIdx.x; i < total;
       i += gridDim.x * blockDim.x) {
    int idx = i;
    if (idx < n1) { Wb_hh0[idx] = f2b(W_hh0[idx]); continue; }
    idx -= n1;
    if (idx < n1) { Wb_ih1[idx] = f2b(W_ih1[idx]); continue; }
    idx -= n1;
    if (idx < n1) { Wb_hh1[idx] = f2b(W_hh1[idx]); continue; }
    idx -= n1;
    if (idx < n2) { Wb_out[idx] = f2b(fc_out_w[idx]); continue; }
    idx -= n2;
    if (idx < n3) {
      int n = idx >> 8, k = idx & 255;
      Wb_ih0z[idx] = f2b(W_ih0[(size_t)n * (E_ + LAT_) + E_ + k]);
      continue;
    }
    idx -= n3;
    if (idx < n4) { Wb_fch[idx] = f2b(fc_hidden_w[idx]); continue; }
    idx -= n4;
    z_b[idx] = f2b(z[idx]);
  }
}

__global__ __launch_bounds__(256) void k_prep_emb(const float* __restrict__ embed,
                                                  const float* __restrict__ W_ih0,
                                                  short* __restrict__ egx) {
  __shared__ float er[E_];
  int v = blockIdx.x;
  for (int e = threadIdx.x; e < E_; e += blockDim.x) er[e] = embed[(size_t)v * E_ + e];
  __syncthreads();
  for (int n = threadIdx.x; n < H3; n += blockDim.x) {
    const float* w = W_ih0 + (size_t)n * (E_ + LAT_);
    float acc = 0.f;
#pragma unroll 8
    for (int e = 0; e < E_; ++e) acc += er[e] * w[e];
    egx[(size_t)v * H3 + n] = f2b(acc);
  }
}

__global__ __launch_bounds__(256) void k_prep1(
    const short* __restrict__ z_b, const short* __restrict__ Wb_ih0z,
    const short* __restrict__ Wb_fch, const float* __restrict__ b_ih0,
    const float* __restrict__ fc_hidden_b,
    short* zgx, float* h0f, float* h1f, short* h0b, short* h1b) {
  const int bid = blockIdx.x;
  const int mtile = bid / 20, ntile = bid % 20;
  const int tid = threadIdx.x, lane = tid & 63, wid = tid >> 6;
  const int wm = wid >> 1, wn = wid & 1;
  const int arow = mtile * 128 + wm * 64;
  f32x4 acc[4][4] = {};
  if (ntile < 12) {
    int bcol = ntile * 128 + wn * 64;
    gemm_wave_global<4, 4>(z_b, Wb_ih0z, LAT_, arow, bcol, acc);
    epi_store_bf16<4, 4>(zgx, b_ih0, H3, arow, bcol, acc);
  } else {
    int bcol = (ntile - 12) * 128 + wn * 64;
    gemm_wave_global<4, 4>(z_b, Wb_fch, LAT_, arow, bcol, acc);
    const int r0 = (lane >> 4) * 4, c0 = lane & 15;
#pragma unroll
    for (int i = 0; i < 4; ++i)
#pragma unroll
      for (int j = 0; j < 4; ++j) {
        int col = bcol + j * 16 + c0;
        float bv = fc_hidden_b[col];
#pragma unroll
        for (int rr = 0; rr < 4; ++rr) {
          int row = arow + i * 16 + r0 + rr;
          float v = acc[i][j][rr] + bv;
          if (col < H_) {
            h0f[(size_t)row * H_ + col] = v;
            h0b[(size_t)row * H_ + col] = f2b(v);
          } else {
            h1f[(size_t)row * H_ + (col - H_)] = v;
            h1b[(size_t)row * H_ + (col - H_)] = f2b(v);
          }
        }
      }
  }
}

extern "C" void kernel_launch(void* const* d_in, const int* in_sizes, int n_in,
                              void* d_out, int out_size, void* d_ws, size_t ws_size,
                              hipStream_t stream) {
  const float* z           = (const float*)d_in[0];
  const int*   target      = (const int*)d_in[1];
  const float* embed       = (const float*)d_in[2];
  const float* fc_hidden_w = (const float*)d_in[3];
  const float* fc_hidden_b = (const float*)d_in[4];
  const float* W_ih0       = (const float*)d_in[5];
  const float* W_hh0       = (const float*)d_in[6];
  const float* b_ih0       = (const float*)d_in[7];
  const float* b_hh0       = (const float*)d_in[8];
  const float* W_ih1       = (const float*)d_in[9];
  const float* W_hh1       = (const float*)d_in[10];
  const float* b_ih1       = (const float*)d_in[11];
  const float* b_hh1       = (const float*)d_in[12];
  const float* fc_out_w    = (const float*)d_in[13];
  const float* fc_out_b    = (const float*)d_in[14];
  float* out = (float*)d_out;

  char* ws = (char*)d_ws;
  size_t off = 0;
  auto alloc = [&](size_t bytes) -> void* {
    off = (off + 255) & ~(size_t)255;
    void* p = ws + off;
    off += bytes;
    return p;
  };
  float* h0f    = (float*)alloc((size_t)B_ * H_ * 4);
  float* h1f    = (float*)alloc((size_t)B_ * H_ * 4);
  short* h0b    = (short*)alloc((size_t)B_ * H_ * 2);
  short* h1b    = (short*)alloc((size_t)B_ * H_ * 2);
  short* p0     = (short*)alloc((size_t)B_ * 4 * H_ * 2);
  short* gx1a   = (short*)alloc((size_t)B_ * H3 * 2);
  short* gx1b   = (short*)alloc((size_t)B_ * H3 * 2);
  short* gh1    = (short*)alloc((size_t)B_ * H3 * 2);
  short* zgx    = (short*)alloc((size_t)B_ * H3 * 2);
  short* egx    = (short*)alloc((size_t)V_ * H3 * 2);
  short* Wb_hh0 = (short*)alloc((size_t)H3 * H_ * 2);
  short* Wb_ih1 = (short*)alloc((size_t)H3 * H_ * 2);
  short* Wb_hh1 = (short*)alloc((size_t)H3 * H_ * 2);
  short* Wb_out = (short*)alloc((size_t)V_ * H_ * 2);
  short* Wb_ih0z= (short*)alloc((size_t)H3 * LAT_ * 2);
  short* Wb_fch = (short*)alloc((size_t)2 * H_ * LAT_ * 2);
  short* z_b    = (short*)alloc((size_t)B_ * LAT_ * 2);
  if (off > ws_size) return;

  k_prep0<<<2048, 256, 0, stream>>>(W_hh0, W_ih1, W_hh1, fc_out_w, W_ih0, fc_hidden_w,
                                    z, Wb_hh0, Wb_ih1, Wb_hh1, Wb_out, Wb_ih0z, Wb_fch, z_b);
  k_prep_emb<<<64, 256, 0, stream>>>(embed, W_ih0, egx);
  k_prep1<<<320, 256, 0, stream>>>(z_b, Wb_ih0z, Wb_fch, b_ih0, fc_hidden_b,
                                   zgx, h0f, h1f, h0b, h1b);

  GArgs a;
  a.zgx = zgx; a.egx = egx; a.target = target;
  a.h0f = h0f; a.h1f = h1f; a.h0b = h0b; a.h1b = h1b;
  a.p0 = p0; a.gx1a = gx1a; a.gx1b = gx1b; a.gh1 = gh1;
  a.Wb_hh0 = Wb_hh0; a.b_hh0 = b_hh0;
  a.Wb_ih1 = Wb_ih1; a.b_ih1 = b_ih1;
  a.Wb_hh1 = Wb_hh1; a.b_hh1 = b_hh1;
  a.Wb_out = Wb_out; a.fc_out_b = fc_out_b;
  a.out = out;

  // Skewed 2-launch pipeline (R6 structure, measured 4389us), + XCD-grouped GEMM tiles:
  //   A(t): G0(t)->p0 | X1(t-1)->gx1[(t-1)&1] | P1(t-2)+logits (reads gx1[t&1])
  //   C(t): Dp(t): pw0(p0)->h0 | G1(t-1)->gh1
  for (int t = 0; t <= T_ + 1; ++t) {
    k_A<<<896, 256, 49152, stream>>>(a, t);
    if (t <= T_) k_C<<<512, 256, 49152, stream>>>(a, t);
  }
}